// Round 11
// baseline (91.750 us; speedup 1.0000x reference)
//
#include <hip/hip_runtime.h>
#include <hip/hip_bf16.h>
#include <math.h>

#define D 300
#define R 5
#define NE 1000000
#define B 32
#define NG 25000
#define NS 25000
#define NROWS 50000
#define NT16 3125      // 16-row j-tiles (50000 = 3125*16)
#define NSB 977        // scan blocks
#define MCAP 16        // matches per scan block (P(>16) ~ 0)
#define HST 324        // hcbL LDS row stride in bf16 (648 B -> ~2-way banks)

typedef __bf16 bf16x8 __attribute__((ext_vector_type(8)));
typedef float f32x4 __attribute__((ext_vector_type(4)));

// ws layout (floats):
//   hcf   [0, 9600)
//   pm2   float2 at 9600: 64 x 3125  -> [9600, 409600)
//   mcntb int   at [409600, 410577)
//   mlist int2  at 410578 (8B aligned) -> [410578, 441842)

__device__ __forceinline__ void online_upd(float& m, float& s, float v) {
    if (v > m) { s = s * __expf(m - v) + 1.0f; m = v; }
    else       { s += __expf(v - m); }
}
__device__ __forceinline__ void online_merge(float& m, float& s, float om, float os) {
    float M = fmaxf(m, om);
    s = s * __expf(m - M) + os * __expf(om - M);
    m = M;
}

// Pass 1: bloom-scan dst; per-block compact match list (no global atomics, no
// pre-zeroed memory). Also zeroes hcf for the NEXT dispatch.
__global__ __launch_bounds__(256) void scan_match(
        const int* __restrict__ ei, const int* __restrict__ et,
        const int* __restrict__ cur,
        int2* __restrict__ mlist, int* __restrict__ mcntb, float* __restrict__ hcf) {
    __shared__ unsigned int tbl[32];
    __shared__ int curl[B];
    __shared__ int lcnt;
    __shared__ int2 loc[MCAP];
    int tid = threadIdx.x;
    int gidx = blockIdx.x * 256 + tid;
    if (gidx < 9600) hcf[gidx] = 0.f;          // zero hcf (read only by later dispatches)
    if (tid < 32) tbl[tid] = 0u;
    if (tid == 0) lcnt = 0;
    __syncthreads();
    if (tid < B) { int c = cur[tid]; curl[tid] = c; atomicOr(&tbl[(c >> 5) & 31], 1u << (c & 31)); }
    __syncthreads();
    long base = ((long)blockIdx.x * 256 + tid) * 4;
    if (base < NE) {
        int ds4[4];
        if (base + 4 <= NE) {
            int4 d4 = *(const int4*)(ei + NE + base);
            ds4[0] = d4.x; ds4[1] = d4.y; ds4[2] = d4.z; ds4[3] = d4.w;
        } else {
            for (int k = 0; k < 4; ++k) ds4[k] = (base + k < NE) ? ei[NE + base + k] : -1;
        }
        #pragma unroll
        for (int k = 0; k < 4; ++k) {
            int dst = ds4[k];
            if (dst < 0) continue;
            if (!(tbl[(dst >> 5) & 31] & (1u << (dst & 31)))) continue;  // bloom reject
            int e = (int)base + k;
            int r = -1, src = 0;
            for (int b = 0; b < B; ++b) {
                if (dst == curl[b]) {
                    if (r < 0) { r = et[e]; src = ei[e]; }
                    int p = atomicAdd(&lcnt, 1);
                    if (p < MCAP) loc[p] = int2{src, b * R + r};
                }
            }
        }
    }
    __syncthreads();
    int n = lcnt < MCAP ? lcnt : MCAP;
    if (tid == 0) mcntb[blockIdx.x] = n;
    if (tid < n) mlist[blockIdx.x * MCAP + tid] = loc[tid];
}

// Pass 2: RGCN transform, 72 blocks x 25-row K-chunks of U[32x1800] @ M[1800x300].
// mc-blocks (kc>=12) gather matches and build their wsum slice in LDS. No done flag.
__global__ __launch_bounds__(320) void rgcn_hc(
        const float* __restrict__ x, const int* __restrict__ cur,
        const float* __restrict__ comp, const float* __restrict__ root,
        const float* __restrict__ basis,
        const int2* __restrict__ mlist, const int* __restrict__ mcntb,
        float* __restrict__ hcf) {
    int kc = blockIdx.x, t = threadIdx.x;
    __shared__ float uL[800];          // 32 b x 25 k
    __shared__ int2 ml[1024];
    __shared__ int mn;
    __shared__ float wsumL[160 * 25];
    __shared__ float cntL[160];
    __shared__ float invL[160];
    __shared__ float cmp[R * R];
    int d0 = kc * 25;

    if (kc < 12) {                     // x-rows chunk: no aggregation needed
        for (int i = t; i < 800; i += 320) {
            int b = i / 25, dd = i - b * 25;
            uL[i] = x[(long)cur[b] * D + d0 + dd];
        }
        __syncthreads();
    } else {
        if (t == 0) mn = 0;
        if (t < R * R) cmp[t] = comp[t];
        for (int i = t; i < 160; i += 320) cntL[i] = 0.f;
        for (int i = t; i < 160 * 25; i += 320) wsumL[i] = 0.f;
        __syncthreads();
        for (int i = t; i < NSB; i += 320) {
            int c = mcntb[i];
            for (int k = 0; k < c; ++k) {
                int p = atomicAdd(&mn, 1);
                if (p < 1024) ml[p] = mlist[i * MCAP + k];
            }
        }
        __syncthreads();
        int n = mn < 1024 ? mn : 1024;
        for (int m = t; m < n; m += 320) atomicAdd(&cntL[ml[m].y], 1.0f);
        __syncthreads();
        for (int i = t; i < 160; i += 320) invL[i] = 1.0f / fmaxf(cntL[i], 1.0f);
        int g2 = kc - 12;
        int bb = g2 / 12, t0 = (g2 - bb * 12) * 25;
        if (t < 300) {                 // 12 match-groups x 25 cols
            int g = t / 25, col = t - g * 25;
            for (int m = g; m < n; m += 12) {
                int2 pr = ml[m];
                atomicAdd(&wsumL[pr.y * 25 + col], x[(long)pr.x * D + t0 + col]);
            }
        }
        __syncthreads();
        for (int i = t; i < 800; i += 320) {
            int b = i / 25, dd = i - b * 25;
            float a = 0.f;
            #pragma unroll
            for (int r = 0; r < R; ++r)
                a = fmaf(cmp[r * R + bb] * invL[b * R + r], wsumL[(b * R + r) * 25 + dd], a);
            uL[i] = a;
        }
        __syncthreads();
    }

    if (t < D) {
        const float* Mb = (kc < 12) ? (root + (long)d0 * D) : (basis + (long)(d0 - 300) * D);
        float acc[B] = {};
        #pragma unroll 5
        for (int i = 0; i < 25; ++i) {
            float m = Mb[(long)i * D + t];
            #pragma unroll
            for (int b = 0; b < B; ++b) acc[b] = fmaf(uL[b * 25 + i], m, acc[b]);
        }
        for (int b = 0; b < B; ++b) atomicAdd(&hcf[b * D + t], acc[b]);
    }
}

// Pass 3: head GEMM. 782 blocks x 4 waves; block stages hc (bias+relu+bf16) from
// hcf into LDS; wave = 16 j-rows x all 32 b (two MFMA chains share one A-frag).
__global__ __launch_bounds__(256) void head_gemm(
    const float* __restrict__ hcf, const float* __restrict__ bias,
    const float* __restrict__ wg, const float* __restrict__ bg,
    const float* __restrict__ wsn, const float* __restrict__ bsn,
    float* __restrict__ out, float2* __restrict__ pm2) {
    __shared__ __bf16 hcbL[32 * HST];
    int tid = threadIdx.x;
    for (int i = tid; i < 32 * HST; i += 256) {
        int b = i / HST, kk = i - b * HST;
        float v = 0.f;
        if (kk < D) v = fmaxf(hcf[b * D + kk] + bias[kk], 0.f);
        hcbL[i] = (__bf16)v;
    }
    __syncthreads();

    int wid = tid >> 6, l = tid & 63, ln = l & 15, og = l >> 4;
    int jt = blockIdx.x * 4 + wid;
    if (jt >= NT16) return;
    int j0 = jt * 16;

    bf16x8 bfrag0[10], bfrag1[10];
    const __bf16* hrow0 = hcbL + ln * HST + og * 8;
    const __bf16* hrow1 = hcbL + (16 + ln) * HST + og * 8;
    #pragma unroll
    for (int s = 0; s < 10; ++s) {
        bfrag0[s] = *(const bf16x8*)(hrow0 + 32 * s);
        bfrag1[s] = *(const bf16x8*)(hrow1 + 32 * s);
    }

    int row = j0 + ln;
    const float* wrow = ((row < NG) ? (wg + (long)row * D) : (wsn + (long)(row - NG) * D)) + og * 8;

    f32x4 acc0 = {}, acc1 = {};
    #pragma unroll
    for (int s = 0; s < 9; ++s) {
        float4 w0 = *(const float4*)(wrow + 32 * s);
        float4 w1 = *(const float4*)(wrow + 32 * s + 4);
        bf16x8 a;
        a[0]=(__bf16)w0.x; a[1]=(__bf16)w0.y; a[2]=(__bf16)w0.z; a[3]=(__bf16)w0.w;
        a[4]=(__bf16)w1.x; a[5]=(__bf16)w1.y; a[6]=(__bf16)w1.z; a[7]=(__bf16)w1.w;
        acc0 = __builtin_amdgcn_mfma_f32_16x16x32_bf16(a, bfrag0[s], acc0, 0, 0, 0);
        acc1 = __builtin_amdgcn_mfma_f32_16x16x32_bf16(a, bfrag1[s], acc1, 0, 0, 0);
    }
    {   // tail: og0 -> k288..295, og1 -> k296..299 (+zeros), og2/3 -> zeros
        float4 w0 = float4{0.f,0.f,0.f,0.f}, w1 = float4{0.f,0.f,0.f,0.f};
        if (og == 0) { w0 = *(const float4*)(wrow + 288); w1 = *(const float4*)(wrow + 292); }
        else if (og == 1) { w0 = *(const float4*)(wrow + 288); }
        bf16x8 a;
        a[0]=(__bf16)w0.x; a[1]=(__bf16)w0.y; a[2]=(__bf16)w0.z; a[3]=(__bf16)w0.w;
        a[4]=(__bf16)w1.x; a[5]=(__bf16)w1.y; a[6]=(__bf16)w1.z; a[7]=(__bf16)w1.w;
        acc0 = __builtin_amdgcn_mfma_f32_16x16x32_bf16(a, bfrag0[9], acc0, 0, 0, 0);
        acc1 = __builtin_amdgcn_mfma_f32_16x16x32_bf16(a, bfrag1[9], acc1, 0, 0, 0);
    }

    int b0 = ln, b1 = 16 + ln;
    float m0 = -3.0e38f, s0 = 0.f, m1 = -3.0e38f, s1 = 0.f;
    float m2 = -3.0e38f, s2 = 0.f, m3 = -3.0e38f, s3 = 0.f;
    #pragma unroll
    for (int r = 0; r < 4; ++r) {
        int j = j0 + og * 4 + r;
        float bv = (j < NG) ? bg[j] : bsn[j - NG];
        float v0 = acc0[r] + bv;
        float v1 = acc1[r] + bv;
        float* op0 = (j < NG) ? (out + (long)b0 * NG + j)
                              : (out + (long)B * NG + (long)b0 * NS + (j - NG));
        float* op1 = (j < NG) ? (out + (long)b1 * NG + j)
                              : (out + (long)B * NG + (long)b1 * NS + (j - NG));
        *op0 = v0;
        *op1 = v1;
        if (j < NG) { online_upd(m0, s0, v0); online_upd(m2, s2, v1); }
        else        { online_upd(m1, s1, v0); online_upd(m3, s3, v1); }
    }
    #pragma unroll
    for (int o = 16; o <= 32; o <<= 1) {
        float tm, ts;
        tm = __shfl_xor(m0, o); ts = __shfl_xor(s0, o); online_merge(m0, s0, tm, ts);
        tm = __shfl_xor(m1, o); ts = __shfl_xor(s1, o); online_merge(m1, s1, tm, ts);
        tm = __shfl_xor(m2, o); ts = __shfl_xor(s2, o); online_merge(m2, s2, tm, ts);
        tm = __shfl_xor(m3, o); ts = __shfl_xor(s3, o); online_merge(m3, s3, tm, ts);
    }
    if (og == 0) {
        pm2[(long)b0 * NT16 + jt]       = float2{m0, s0};
        pm2[(long)(B + b0) * NT16 + jt] = float2{m1, s1};
        pm2[(long)b1 * NT16 + jt]       = float2{m2, s2};
        pm2[(long)(B + b1) * NT16 + jt] = float2{m3, s3};
    }
}

// Pass 4: fused lse reduce (per-row strip, L2-hot) + subtract over a 1000-float chunk.
__global__ __launch_bounds__(256) void lse_sub(float* __restrict__ out,
                                               const float2* __restrict__ pm2) {
    int rw = blockIdx.x / 25, c = blockIdx.x % 25;
    int tid = threadIdx.x;
    const float2* pr = pm2 + (long)rw * NT16;
    float m = -3.0e38f, s = 0.f;
    for (int i = tid; i < NT16; i += 256) { float2 e = pr[i]; online_merge(m, s, e.x, e.y); }
    #pragma unroll
    for (int o = 32; o; o >>= 1) {
        float om = __shfl_xor(m, o), os = __shfl_xor(s, o);
        online_merge(m, s, om, os);
    }
    __shared__ float sm[4], ss[4];
    __shared__ float lseS;
    if ((tid & 63) == 0) { sm[tid >> 6] = m; ss[tid >> 6] = s; }
    __syncthreads();
    if (tid == 0) {
        float M = sm[0], S = ss[0];
        for (int w = 1; w < 4; ++w) online_merge(M, S, sm[w], ss[w]);
        lseS = M + __logf(S);
    }
    __syncthreads();
    float l = lseS;
    float4* o4 = (float4*)out + (long)rw * 6250 + c * 250;
    if (tid < 250) { float4 v = o4[tid]; v.x -= l; v.y -= l; v.z -= l; v.w -= l; o4[tid] = v; }
}

extern "C" void kernel_launch(void* const* d_in, const int* in_sizes, int n_in,
                              void* d_out, int out_size, void* d_ws, size_t ws_size,
                              hipStream_t stream) {
    const float* x     = (const float*)d_in[0];
    const int*   ei    = (const int*)d_in[1];
    const int*   et    = (const int*)d_in[2];
    const int*   cur   = (const int*)d_in[3];
    const float* basis = (const float*)d_in[4];
    const float* comp  = (const float*)d_in[5];
    const float* root  = (const float*)d_in[6];
    const float* bias  = (const float*)d_in[7];
    const float* wg    = (const float*)d_in[8];
    const float* bgl   = (const float*)d_in[9];
    const float* wsn   = (const float*)d_in[10];
    const float* bsn   = (const float*)d_in[11];
    float* out  = (float*)d_out;
    float* wsf  = (float*)d_ws;
    float*  hcf   = wsf;                        // [0, 9600)
    float2* pm2   = (float2*)(wsf + 9600);      // 64 x 3125
    int*    mcntb = (int*)(wsf + 409600);       // 977 ints
    int2*   mlist = (int2*)(wsf + 410578);      // 977 x 16 int2

    scan_match<<<NSB, 256, 0, stream>>>(ei, et, cur, mlist, mcntb, hcf);
    rgcn_hc<<<72, 320, 0, stream>>>(x, cur, comp, root, basis, mlist, mcntb, hcf);
    head_gemm<<<(NT16 + 3) / 4, 256, 0, stream>>>(hcf, bias, wg, bgl, wsn, bsn, out, pm2);
    lse_sub<<<1600, 256, 0, stream>>>(out, pm2);
}

// Round 12
// 74.700 us; speedup vs baseline: 1.2282x; 1.2282x over previous
//
#include <hip/hip_runtime.h>
#include <hip/hip_bf16.h>
#include <math.h>

#define D 300
#define R 5
#define NE 1000000
#define B 32
#define NG 25000
#define NS 25000
#define NROWS 50000
#define NT16 3125      // 16-row j-tiles (50000 = 3125*16)
#define HST 324        // hcbL LDS row stride in bf16 (648 B)

typedef __bf16 bf16x8 __attribute__((ext_vector_type(8)));
typedef float f32x4 __attribute__((ext_vector_type(4)));

// ws layout (floats):
//   wsum [0, 48000)  wcnt [48000, 48160)  hcf [48160, 57760)
//   pm2  float2 at 57760: 64 x 3125 -> [57760, 457760)

__device__ __forceinline__ void online_upd(float& m, float& s, float v) {
    if (v > m) { s = s * __expf(m - v) + 1.0f; m = v; }
    else       { s += __expf(v - m); }
}
__device__ __forceinline__ void online_merge(float& m, float& s, float om, float os) {
    float M = fmaxf(m, om);
    s = s * __expf(m - M) + os * __expf(om - M);
    m = M;
}

__global__ void zero_ws(float4* __restrict__ p) {
    int i = blockIdx.x * 256 + threadIdx.x;
    if (i < 14440) p[i] = float4{0.f, 0.f, 0.f, 0.f};  // wsum|wcnt|hcf
}

// Proven (R4-R7): bloom dst scan, LDS-compact matches, coalesced 300-float row-adds.
__global__ __launch_bounds__(256) void scan_accum(
        const int* __restrict__ ei, const int* __restrict__ et,
        const int* __restrict__ cur, const float* __restrict__ x,
        float* __restrict__ wsum, float* __restrict__ wcnt) {
    __shared__ unsigned int tbl[32];
    __shared__ int curl[B];
    __shared__ int lcnt;
    __shared__ int2 loc[64];
    int tid = threadIdx.x;
    if (tid < 32) tbl[tid] = 0u;
    if (tid == 0) lcnt = 0;
    __syncthreads();
    if (tid < B) { int c = cur[tid]; curl[tid] = c; atomicOr(&tbl[(c >> 5) & 31], 1u << (c & 31)); }
    __syncthreads();
    long base = ((long)blockIdx.x * 256 + tid) * 4;
    if (base < NE) {
        int ds4[4];
        if (base + 4 <= NE) {
            int4 d4 = *(const int4*)(ei + NE + base);
            ds4[0] = d4.x; ds4[1] = d4.y; ds4[2] = d4.z; ds4[3] = d4.w;
        } else {
            for (int k = 0; k < 4; ++k) ds4[k] = (base + k < NE) ? ei[NE + base + k] : -1;
        }
        #pragma unroll
        for (int k = 0; k < 4; ++k) {
            int dst = ds4[k];
            if (dst < 0) continue;
            if (!(tbl[(dst >> 5) & 31] & (1u << (dst & 31)))) continue;  // bloom reject
            int e = (int)base + k;
            int r = -1, src = 0;
            for (int b = 0; b < B; ++b) {
                if (dst == curl[b]) {
                    if (r < 0) { r = et[e]; src = ei[e]; }
                    atomicAdd(&wcnt[b * R + r], 1.0f);
                    int p = atomicAdd(&lcnt, 1);
                    if (p < 64) loc[p] = int2{src, b * R + r};
                }
            }
        }
    }
    __syncthreads();
    int n = lcnt; if (n > 64) n = 64;
    for (int m = 0; m < n; ++m) {
        int2 pr = loc[m];
        const float* xs = x + (long)pr.x * D;
        float* sm = wsum + (long)pr.y * D;
        for (int t = tid; t < D; t += 256) atomicAdd(&sm[t], xs[t]);
    }
}

// Proven (R7): 72 blocks x 25-row K-chunks of U[32x1800] @ M[1800x300]; no flag.
__global__ __launch_bounds__(320) void rgcn_hc(
        const float* __restrict__ x, const int* __restrict__ cur,
        const float* __restrict__ comp, const float* __restrict__ root,
        const float* __restrict__ basis, const float* __restrict__ wsum,
        const float* __restrict__ wcnt, float* __restrict__ hcf) {
    int kc = blockIdx.x, t = threadIdx.x;
    __shared__ float uL[800];       // 32 b x 25 k
    __shared__ float inv[B * R];
    __shared__ float cmp[R * R];
    if (t < B * R) inv[t] = 1.0f / fmaxf(wcnt[t], 1.0f);
    if (t >= 160 && t < 160 + R * R) cmp[t - 160] = comp[t - 160];
    __syncthreads();
    int d0 = kc * 25;
    if (d0 < 300) {
        for (int i = t; i < 800; i += 320) {
            int b = i / 25, dd = i - b * 25;
            uL[i] = x[(long)cur[b] * D + d0 + dd];
        }
    } else {
        int g0 = d0 - 300;
        int bb = g0 / 300, t0 = g0 - bb * 300;   // 25 | 300, no straddle
        for (int i = t; i < 800; i += 320) {
            int b = i / 25, dd = i - b * 25;
            float a = 0.f;
            #pragma unroll
            for (int r = 0; r < R; ++r)
                a = fmaf(cmp[r * R + bb] * inv[b * R + r], wsum[(long)(b * R + r) * D + t0 + dd], a);
            uL[i] = a;
        }
    }
    __syncthreads();
    if (t < D) {
        const float* Mb = (d0 < 300) ? (root + (long)d0 * D) : (basis + (long)(d0 - 300) * D);
        float acc[B] = {};
        #pragma unroll 5
        for (int i = 0; i < 25; ++i) {
            float m = Mb[(long)i * D + t];
            #pragma unroll
            for (int b = 0; b < B; ++b) acc[b] = fmaf(uL[b * 25 + i], m, acc[b]);
        }
        for (int b = 0; b < B; ++b) atomicAdd(&hcf[b * D + t], acc[b]);
    }
}

// Head GEMM v3: wave = 16 j x all 32 b; lane preloads its ENTIRE W segment
// (20 float4, fully unrolled, sched_barrier-pinned) -> deep VMEM pipeline.
__global__ __launch_bounds__(256) void head_gemm(
    const float* __restrict__ hcf, const float* __restrict__ bias,
    const float* __restrict__ wg, const float* __restrict__ bg,
    const float* __restrict__ wsn, const float* __restrict__ bsn,
    float* __restrict__ out, float2* __restrict__ pm2) {
    __shared__ __bf16 hcbL[32 * HST];
    int tid = threadIdx.x;
    for (int i = tid; i < 32 * HST; i += 256) {
        int b = i / HST, kk = i - b * HST;
        float v = 0.f;
        if (kk < D) v = fmaxf(hcf[b * D + kk] + bias[kk], 0.f);
        hcbL[i] = (__bf16)v;
    }
    __syncthreads();

    int wid = tid >> 6, l = tid & 63, ln = l & 15, og = l >> 4;
    int jt = blockIdx.x * 4 + wid;
    if (jt >= NT16) return;
    int j0 = jt * 16;
    int row = j0 + ln;
    const float* wrow = ((row < NG) ? (wg + (long)row * D) : (wsn + (long)(row - NG) * D)) + og * 8;

    // ---- load phase: all 20 float4 in flight before any compute ----
    float4 w[20];
    #pragma unroll
    for (int s = 0; s < 9; ++s) {
        w[2 * s]     = *(const float4*)(wrow + 32 * s);
        w[2 * s + 1] = *(const float4*)(wrow + 32 * s + 4);
    }
    {   // tail step: og0 -> k288..295; og1 -> k296..299 (+zeros); og2/3 -> zeros
        w[18] = float4{0.f, 0.f, 0.f, 0.f};
        w[19] = float4{0.f, 0.f, 0.f, 0.f};
        if (og == 0) { w[18] = *(const float4*)(wrow + 288); w[19] = *(const float4*)(wrow + 292); }
        else if (og == 1) { w[18] = *(const float4*)(wrow + 288); }
    }
    __builtin_amdgcn_sched_barrier(0);

    // ---- compute phase ----
    const __bf16* hrow0 = hcbL + ln * HST + og * 8;
    const __bf16* hrow1 = hcbL + (16 + ln) * HST + og * 8;
    f32x4 acc0 = {}, acc1 = {};
    #pragma unroll
    for (int s = 0; s < 10; ++s) {
        float4 w0 = w[2 * s], w1 = w[2 * s + 1];
        bf16x8 a;
        a[0]=(__bf16)w0.x; a[1]=(__bf16)w0.y; a[2]=(__bf16)w0.z; a[3]=(__bf16)w0.w;
        a[4]=(__bf16)w1.x; a[5]=(__bf16)w1.y; a[6]=(__bf16)w1.z; a[7]=(__bf16)w1.w;
        acc0 = __builtin_amdgcn_mfma_f32_16x16x32_bf16(a, *(const bf16x8*)(hrow0 + 32 * s), acc0, 0, 0, 0);
        acc1 = __builtin_amdgcn_mfma_f32_16x16x32_bf16(a, *(const bf16x8*)(hrow1 + 32 * s), acc1, 0, 0, 0);
    }

    // ---- epilogue (verified mapping: col=b, row=og*4+r) ----
    int b0 = ln, b1 = 16 + ln;
    float m0 = -3.0e38f, s0 = 0.f, m1 = -3.0e38f, s1 = 0.f;
    float m2 = -3.0e38f, s2 = 0.f, m3 = -3.0e38f, s3 = 0.f;
    #pragma unroll
    for (int r = 0; r < 4; ++r) {
        int j = j0 + og * 4 + r;
        float bv = (j < NG) ? bg[j] : bsn[j - NG];
        float v0 = acc0[r] + bv;
        float v1 = acc1[r] + bv;
        float* op0 = (j < NG) ? (out + (long)b0 * NG + j)
                              : (out + (long)B * NG + (long)b0 * NS + (j - NG));
        float* op1 = (j < NG) ? (out + (long)b1 * NG + j)
                              : (out + (long)B * NG + (long)b1 * NS + (j - NG));
        *op0 = v0;
        *op1 = v1;
        if (j < NG) { online_upd(m0, s0, v0); online_upd(m2, s2, v1); }
        else        { online_upd(m1, s1, v0); online_upd(m3, s3, v1); }
    }
    #pragma unroll
    for (int o = 16; o <= 32; o <<= 1) {
        float tm, ts;
        tm = __shfl_xor(m0, o); ts = __shfl_xor(s0, o); online_merge(m0, s0, tm, ts);
        tm = __shfl_xor(m1, o); ts = __shfl_xor(s1, o); online_merge(m1, s1, tm, ts);
        tm = __shfl_xor(m2, o); ts = __shfl_xor(s2, o); online_merge(m2, s2, tm, ts);
        tm = __shfl_xor(m3, o); ts = __shfl_xor(s3, o); online_merge(m3, s3, tm, ts);
    }
    if (og == 0) {
        pm2[(long)b0 * NT16 + jt]       = float2{m0, s0};
        pm2[(long)(B + b0) * NT16 + jt] = float2{m1, s1};
        pm2[(long)b1 * NT16 + jt]       = float2{m2, s2};
        pm2[(long)(B + b1) * NT16 + jt] = float2{m3, s3};
    }
}

// Fused lse reduce (L2-hot strip, redundant per 25 chunk-blocks) + subtract.
__global__ __launch_bounds__(256) void lse_sub(float* __restrict__ out,
                                               const float2* __restrict__ pm2) {
    int rw = blockIdx.x / 25, c = blockIdx.x % 25;
    int tid = threadIdx.x;
    const float2* pr = pm2 + (long)rw * NT16;
    float m = -3.0e38f, s = 0.f;
    for (int i = tid; i < NT16; i += 256) { float2 e = pr[i]; online_merge(m, s, e.x, e.y); }
    #pragma unroll
    for (int o = 32; o; o >>= 1) {
        float om = __shfl_xor(m, o), os = __shfl_xor(s, o);
        online_merge(m, s, om, os);
    }
    __shared__ float sm[4], ss[4];
    __shared__ float lseS;
    if ((tid & 63) == 0) { sm[tid >> 6] = m; ss[tid >> 6] = s; }
    __syncthreads();
    if (tid == 0) {
        float M = sm[0], S = ss[0];
        for (int w = 1; w < 4; ++w) online_merge(M, S, sm[w], ss[w]);
        lseS = M + __logf(S);
    }
    __syncthreads();
    float l = lseS;
    float4* o4 = (float4*)out + (long)rw * 6250 + c * 250;
    if (tid < 250) { float4 v = o4[tid]; v.x -= l; v.y -= l; v.z -= l; v.w -= l; o4[tid] = v; }
}

extern "C" void kernel_launch(void* const* d_in, const int* in_sizes, int n_in,
                              void* d_out, int out_size, void* d_ws, size_t ws_size,
                              hipStream_t stream) {
    const float* x     = (const float*)d_in[0];
    const int*   ei    = (const int*)d_in[1];
    const int*   et    = (const int*)d_in[2];
    const int*   cur   = (const int*)d_in[3];
    const float* basis = (const float*)d_in[4];
    const float* comp  = (const float*)d_in[5];
    const float* root  = (const float*)d_in[6];
    const float* bias  = (const float*)d_in[7];
    const float* wg    = (const float*)d_in[8];
    const float* bgl   = (const float*)d_in[9];
    const float* wsn   = (const float*)d_in[10];
    const float* bsn   = (const float*)d_in[11];
    float* out  = (float*)d_out;
    float* wsf  = (float*)d_ws;
    float*  wsum = wsf;                        // [0, 48000)
    float*  wcnt = wsf + 48000;                // [48000, 48160)
    float*  hcf  = wsf + 48160;                // [48160, 57760)
    float2* pm2  = (float2*)(wsf + 57760);     // 64 x 3125

    zero_ws<<<57, 256, 0, stream>>>((float4*)d_ws);
    scan_accum<<<977, 256, 0, stream>>>(ei, et, cur, x, wsum, wcnt);
    rgcn_hc<<<72, 320, 0, stream>>>(x, cur, comp, root, basis, wsum, wcnt, hcf);
    head_gemm<<<(NT16 + 3) / 4, 256, 0, stream>>>(hcf, bias, wg, bgl, wsn, bsn, out, pm2);
    lse_sub<<<1600, 256, 0, stream>>>(out, pm2);
}